// Round 9
// baseline (877.591 us; speedup 1.0000x reference)
//
#include <hip/hip_runtime.h>
#include <stdint.h>

#define N_PTS 2048
#define NK 5
#define TOPK 512
#define NBINS 4096
#define SCAP 4096

// ws layout (bytes):
//      0  src_ne_idx   int[2048*5]   (40960)
//  40960  src_ne_dist  float[2048*5] (40960)
//  81920  ref_ne_idx   int[2048*5]   (40960)
// 122880  ref_ne_dist  float[2048*5] (40960)
// 163840  hist1        uint[4096]    (16384)   coarse: vb>>20
// 180224  hist2        uint[4096]    (16384)   fine:  (vb>>8)&0xFFF within bin B
// 196608  counters     uint[8]       (32)  [0]=cand_count [1]=B [2]=cumAbove [3]=T
// 196640  cand         uint64[SCAP]
#define OFF_SIDX   0
#define OFF_SDIST  40960
#define OFF_RIDX   81920
#define OFF_RDIST  122880
#define OFF_HIST1  163840
#define OFF_HIST2  180224
#define OFF_CNT    196608
#define OFF_CAND   196640

// ---------------- KNN: blocks 0..7 = src, 8..15 = ref; 1 thread per point ----
// Distance matches XLA-CPU contraction: d2 = fma(dz,dz, fma(dx,dx, dy*dy)).
// Tie rule: lower index first (jax top_k stable rule; proven no-op on data).
__global__ __launch_bounds__(256) void knn_kernel(
    const float* __restrict__ src, const float* __restrict__ ref,
    int* __restrict__ sidx, float* __restrict__ sdist,
    int* __restrict__ ridx, float* __restrict__ rdist) {
  __shared__ float sx[N_PTS], sy[N_PTS], sz[N_PTS];
  const bool is_ref = blockIdx.x >= (N_PTS / 256);
  const float* pts = is_ref ? ref : src;
  int*   oidx  = is_ref ? ridx : sidx;
  float* odist = is_ref ? rdist : sdist;
  const int blk = is_ref ? (blockIdx.x - (N_PTS / 256)) : blockIdx.x;

  for (int t = threadIdx.x; t < N_PTS; t += 256) {
    sx[t] = pts[3 * t + 0];
    sy[t] = pts[3 * t + 1];
    sz[t] = pts[3 * t + 2];
  }
  __syncthreads();

  const int i = blk * 256 + threadIdx.x;
  const float px = sx[i], py = sy[i], pz = sz[i];

  float bd[NK + 1];
  int   bi[NK + 1];
#pragma unroll
  for (int k = 0; k <= NK; ++k) { bd[k] = __builtin_inff(); bi[k] = -1; }

  for (int j = 0; j < N_PTS; ++j) {
    float dx = __fsub_rn(px, sx[j]);
    float dy = __fsub_rn(py, sy[j]);
    float dz = __fsub_rn(pz, sz[j]);
    // XLA/LLVM fmuladd contraction of dx*dx + dy*dy + dz*dz:
    //   fadd(fmul(dx,dx), fmul(dy,dy)) -> fma(dx,dx, dy*dy)
    //   fadd(prev, fmul(dz,dz))        -> fma(dz,dz, prev)
    float d2 = __builtin_fmaf(dz, dz,
                 __builtin_fmaf(dx, dx, __fmul_rn(dy, dy)));
    float d = __fsqrt_rn(fmaxf(d2, 0.0f));
    if (d < bd[NK]) {
      // strict < keeps earlier (lower-index) entries first on exact ties
#pragma unroll
      for (int k = NK; k >= 1; --k) {
        if (d < bd[k - 1])      { bd[k] = bd[k - 1]; bi[k] = bi[k - 1]; }
        else if (d < bd[k])     { bd[k] = d;         bi[k] = j; }
      }
      if (d < bd[0]) { bd[0] = d; bi[0] = j; }
    }
  }
#pragma unroll
  for (int m = 0; m < NK; ++m) {       // drop slot 0 (self)
    oidx[i * NK + m]  = bi[m + 1];
    odist[i * NK + m] = bd[m + 1];
  }
}

// Shared device helper: recompute one s-row's worth of pa values and feed a
// visitor. PASS = 0: coarse hist, 1: fine hist (bin B only), 2: collect.
template <int PASS>
__device__ __forceinline__ void pa_row_pass(
    const float* __restrict__ L,
    const int* __restrict__ sidx, const float* __restrict__ sdist,
    const int* __restrict__ ridx, const float* __restrict__ rdist,
    int s, int tid,
    float (&A)[NK][N_PTS],
    unsigned int* lh, unsigned int B, unsigned int T,
    unsigned int* counters, uint64_t* cand, unsigned int cap) {
  __shared__ float sdsh[NK];
  __shared__ int   snsh[NK];
  if (tid < NK) { snsh[tid] = sidx[s * NK + tid]; sdsh[tid] = sdist[s * NK + tid]; }
  __syncthreads();
#pragma unroll
  for (int i = 0; i < NK; ++i) {
    const int row = snsh[i];
    for (int c = tid; c < N_PTS; c += 256) A[i][c] = L[row * N_PTS + c];
  }
  __syncthreads();
  float sd[NK];
#pragma unroll
  for (int i = 0; i < NK; ++i) sd[i] = sdsh[i];

  for (int r = tid; r < N_PTS; r += 256) {
    const float Lsr = L[s * N_PTS + r];
    float rd[NK]; int rn[NK];
#pragma unroll
    for (int j = 0; j < NK; ++j) { rd[j] = rdist[r * NK + j]; rn[j] = ridx[r * NK + j]; }
#pragma unroll
    for (int i = 0; i < NK; ++i) {
#pragma unroll
      for (int j = 0; j < NK; ++j) {
        float diff = __fsub_rn(sd[i], rd[j]);
        float q    = __fdiv_rn(__fmul_rn(diff, diff), 0.01f);
        float temp = fmaxf(__fsub_rn(1.0f, q), 0.0f);
        if (temp > 0.0f) {
          float v = __fmul_rn(__fmul_rn(Lsr, temp), A[i][rn[j]]);
          if (v > 0.0f) {
            unsigned int vb = __float_as_uint(v);
            if (PASS == 0) {
              atomicAdd(&lh[vb >> 20], 1u);
            } else if (PASS == 1) {
              if ((vb >> 20) == B) atomicAdd(&lh[(vb >> 8) & 0xFFFu], 1u);
            } else {
              if (vb >= T) {
                unsigned int pos = atomicAdd(&counters[0], 1u);
                if (pos < cap) {
                  unsigned int idx = ((unsigned int)(s * N_PTS + r)) * 25u
                                   + (unsigned int)(i * NK + j);
                  // key: value desc; equal values sort idx ASCENDING
                  cand[pos] = (((uint64_t)vb) << 32) | (uint64_t)((uint32_t)(~idx));
                }
              }
            }
          }
        }
      }
    }
  }
}

// ---------------- pass A: coarse 12-bit histogram ----------------------------
__global__ __launch_bounds__(256) void hist1_kernel(
    const float* __restrict__ L,
    const int* __restrict__ sidx, const float* __restrict__ sdist,
    const int* __restrict__ ridx, const float* __restrict__ rdist,
    unsigned int* __restrict__ ghist) {
  __shared__ float A[NK][N_PTS];
  __shared__ unsigned int lh[NBINS];
  const int s = blockIdx.x, tid = threadIdx.x;
  for (int b = tid; b < NBINS; b += 256) lh[b] = 0;
  pa_row_pass<0>(L, sidx, sdist, ridx, rdist, s, tid, A, lh, 0, 0, 0, 0, 0);
  __syncthreads();
  for (int b = tid; b < NBINS; b += 256)
    if (lh[b]) atomicAdd(&ghist[b], lh[b]);
}

// ---------------- scan1: coarse bin B + count strictly above B ---------------
__global__ __launch_bounds__(1024) void scan1_kernel(
    const unsigned int* __restrict__ ghist, unsigned int* __restrict__ counters) {
  __shared__ unsigned int part[1024];
  const int tid = threadIdx.x;
  unsigned int ssum = 0;
#pragma unroll
  for (int b = tid * 4; b < tid * 4 + 4; ++b) ssum += ghist[b];
  part[tid] = ssum;
  __syncthreads();
  if (tid == 0) {
    unsigned int cum = 0, B = 0, cumAbove = 0;
    for (int t = 1023; t >= 0; --t) {
      if (cum + part[t] >= TOPK) {
        for (int b = t * 4 + 3; b >= t * 4; --b) {
          if (cum + ghist[b] >= TOPK) { B = (unsigned int)b; cumAbove = cum; break; }
          cum += ghist[b];
        }
        break;
      }
      cum += part[t];
    }
    counters[1] = B;
    counters[2] = cumAbove;   // < TOPK by construction
  }
}

// ---------------- pass B: fine 12-bit sub-histogram inside bin B -------------
__global__ __launch_bounds__(256) void hist2_kernel(
    const float* __restrict__ L,
    const int* __restrict__ sidx, const float* __restrict__ sdist,
    const int* __restrict__ ridx, const float* __restrict__ rdist,
    const unsigned int* __restrict__ counters, unsigned int* __restrict__ ghist2) {
  __shared__ float A[NK][N_PTS];
  __shared__ unsigned int lh[NBINS];
  const int s = blockIdx.x, tid = threadIdx.x;
  const unsigned int B = counters[1];
  for (int b = tid; b < NBINS; b += 256) lh[b] = 0;
  pa_row_pass<1>(L, sidx, sdist, ridx, rdist, s, tid, A, lh, B, 0, 0, 0, 0);
  __syncthreads();
  for (int b = tid; b < NBINS; b += 256)
    if (lh[b]) atomicAdd(&ghist2[b], lh[b]);
}

// ---------------- scan2: refined threshold T ---------------------------------
__global__ __launch_bounds__(1024) void scan2_kernel(
    const unsigned int* __restrict__ ghist2, unsigned int* __restrict__ counters) {
  __shared__ unsigned int part[1024];
  const int tid = threadIdx.x;
  unsigned int ssum = 0;
#pragma unroll
  for (int b = tid * 4; b < tid * 4 + 4; ++b) ssum += ghist2[b];
  part[tid] = ssum;
  __syncthreads();
  if (tid == 0) {
    const unsigned int B = counters[1];
    unsigned int cum = counters[2];
    unsigned int T = B << 20;           // fallback: whole bin B and above
    for (int t = 1023; t >= 0; --t) {
      if (cum + part[t] >= TOPK) {
        for (int b = t * 4 + 3; b >= t * 4; --b) {
          if (cum + ghist2[b] >= TOPK) { T = (B << 20) | (((unsigned int)b) << 8); break; }
          cum += ghist2[b];
        }
        break;
      }
      cum += part[t];
    }
    counters[3] = T;
  }
}

// ---------------- pass C: collect candidate keys >= T ------------------------
__global__ __launch_bounds__(256) void collect_kernel(
    const float* __restrict__ L,
    const int* __restrict__ sidx, const float* __restrict__ sdist,
    const int* __restrict__ ridx, const float* __restrict__ rdist,
    unsigned int* __restrict__ counters, uint64_t* __restrict__ cand,
    unsigned int cap) {
  __shared__ float A[NK][N_PTS];
  const int s = blockIdx.x, tid = threadIdx.x;
  const unsigned int T = counters[3];
  pa_row_pass<2>(L, sidx, sdist, ridx, rdist, s, tid, A, nullptr, 0, T,
                 counters, cand, cap);
}

// ---------------- top-512: sort-all, value desc / idx asc on ties ------------
__global__ __launch_bounds__(1024) void select_kernel(
    const uint64_t* __restrict__ cand, const unsigned int* __restrict__ counters,
    const int* __restrict__ sidx, const int* __restrict__ ridx,
    int* __restrict__ out, unsigned int cap) {
  __shared__ uint64_t keys[SCAP];
  const int tid = threadIdx.x;
  unsigned int n = counters[0];
  if (n > cap) n = cap;
  if (n > SCAP) n = SCAP;
  for (int t = tid; t < SCAP; t += 1024)
    keys[t] = (t < (int)n) ? cand[t] : 0ull;      // pad sinks (vb=0 < any real)
  __syncthreads();

  // bitonic sort, overall DESCENDING on key=(vb<<32)|~idx  => vb desc, idx asc
  for (int k2 = 2; k2 <= SCAP; k2 <<= 1) {
    for (int j2 = k2 >> 1; j2 > 0; j2 >>= 1) {
      for (int e = 0; e < SCAP / 1024; ++e) {
        int i = tid + e * 1024;
        int pj = i ^ j2;
        if (pj > i) {
          bool blk = ((i & k2) == 0);
          uint64_t a = keys[i], b = keys[pj];
          if (blk ? (a < b) : (a > b)) { keys[i] = b; keys[pj] = a; }
        }
      }
      __syncthreads();
    }
  }

  if (tid < TOPK) {
    uint64_t key = keys[tid];
    unsigned int idx = ~((unsigned int)key);
    if (idx >= 104857600u) idx = 0;           // safety clamp (degenerate only)
    unsigned int s   = idx / 51200u;          // n_r*K*K = 2048*25
    unsigned int rem = idx % 51200u;
    unsigned int r   = rem / 25u;
    unsigned int sij = rem % 25u;
    out[0 * TOPK + tid] = (int)s;                       // first_node_src
    out[1 * TOPK + tid] = (int)r;                       // first_node_ref
    out[2 * TOPK + tid] = sidx[s * NK + sij / 5u];      // second_node_src
    out[3 * TOPK + tid] = ridx[r * NK + sij % 5u];      // second_node_ref
  }
}

extern "C" void kernel_launch(void* const* d_in, const int* in_sizes, int n_in,
                              void* d_out, int out_size, void* d_ws, size_t ws_size,
                              hipStream_t stream) {
  const float* src = (const float*)d_in[0];
  const float* ref = (const float*)d_in[1];
  const float* L   = (const float*)d_in[2];
  char* ws = (char*)d_ws;
  int*          sidx  = (int*)(ws + OFF_SIDX);
  float*        sdist = (float*)(ws + OFF_SDIST);
  int*          ridx  = (int*)(ws + OFF_RIDX);
  float*        rdist = (float*)(ws + OFF_RDIST);
  unsigned int* g1    = (unsigned int*)(ws + OFF_HIST1);
  unsigned int* g2    = (unsigned int*)(ws + OFF_HIST2);
  unsigned int* cnts  = (unsigned int*)(ws + OFF_CNT);
  uint64_t*     cand  = (uint64_t*)(ws + OFF_CAND);
  int*          out   = (int*)d_out;

  unsigned int cap = SCAP;
  if (ws_size > (size_t)OFF_CAND + 8) {
    size_t c = (ws_size - (size_t)OFF_CAND) / 8;
    if (c < cap) cap = (unsigned int)c;
  }

  hipMemsetAsync(ws + OFF_HIST1, 0, 2 * NBINS * 4 + 32, stream);
  knn_kernel<<<16, 256, 0, stream>>>(src, ref, sidx, sdist, ridx, rdist);
  hist1_kernel<<<N_PTS, 256, 0, stream>>>(L, sidx, sdist, ridx, rdist, g1);
  scan1_kernel<<<1, 1024, 0, stream>>>(g1, cnts);
  hist2_kernel<<<N_PTS, 256, 0, stream>>>(L, sidx, sdist, ridx, rdist, cnts, g2);
  scan2_kernel<<<1, 1024, 0, stream>>>(g2, cnts);
  collect_kernel<<<N_PTS, 256, 0, stream>>>(L, sidx, sdist, ridx, rdist, cnts, cand, cap);
  select_kernel<<<1, 1024, 0, stream>>>(cand, cnts, sidx, ridx, out, cap);
}

// Round 10
// 359.775 us; speedup vs baseline: 2.4393x; 2.4393x over previous
//
#include <hip/hip_runtime.h>
#include <stdint.h>

#define N_PTS 2048
#define NK 5
#define TOPK 512
#define CAP_MAX 262144u

// frozen arithmetic (r9-verified bit-exact vs np oracle):
//   d2 = fma(dz,dz, fma(dx,dx, dy*dy)); d = sqrt(max(d2,0))
//   q = fdiv(diff*diff, 0.01f); temp = max(1-q,0); v = (L*temp)*A
// tie rule: value desc, flat idx asc (key (vb<<32)|~idx descending)

// ws layout (bytes):
//      0  src_ne_idx   int[2048*5]   (40960)
//  40960  src_ne_dist  float[2048*5] (40960)
//  81920  ref_ne_idx   int[2048*5]   (40960)
// 122880  ref_ne_dist  float[2048*5] (40960)
// 163840  rowmax       uint[2048]    (8192)
// 172032  counters     uint[8]       (32)   [0]=cand_count [3]=T
// 172064  cand         uint64[cap]
#define OFF_SIDX   0
#define OFF_SDIST  40960
#define OFF_RIDX   81920
#define OFF_RDIST  122880
#define OFF_RMAX   163840
#define OFF_CNT    172032
#define OFF_CAND   172064

__device__ __forceinline__ unsigned long long shflxor64(unsigned long long v, int mask) {
  unsigned lo = (unsigned)v, hi = (unsigned)(v >> 32);
  lo = (unsigned)__shfl_xor((int)lo, mask);
  hi = (unsigned)__shfl_xor((int)hi, mask);
  return ((unsigned long long)hi << 32) | lo;
}

// ---------------- KNN: 512 blocks, 8 points/block, 32 lanes/point ------------
// key = (d_bits<<32)|j : lexicographic min-6 == (d asc, idx asc) — identical
// result to r9's sequential strict-< insertion (d bits identical, keys unique).
__global__ __launch_bounds__(256) void knn_kernel(
    const float* __restrict__ src, const float* __restrict__ ref,
    int* __restrict__ sidx, float* __restrict__ sdist,
    int* __restrict__ ridx, float* __restrict__ rdist) {
  __shared__ float sx[N_PTS], sy[N_PTS], sz[N_PTS];
  const bool is_ref = blockIdx.x >= 256;
  const float* pts = is_ref ? ref : src;
  int*   oidx  = is_ref ? ridx : sidx;
  float* odist = is_ref ? rdist : sdist;
  const int blk = is_ref ? (blockIdx.x - 256) : blockIdx.x;

  for (int t = threadIdx.x; t < N_PTS; t += 256) {
    sx[t] = pts[3 * t + 0];
    sy[t] = pts[3 * t + 1];
    sz[t] = pts[3 * t + 2];
  }
  __syncthreads();

  const int p = blk * 8 + (threadIdx.x >> 5);   // this group's point
  const int u = threadIdx.x & 31;               // lane within 32-lane group
  const float px = sx[p], py = sy[p], pz = sz[p];

  unsigned long long best[6];
#pragma unroll
  for (int k = 0; k < 6; ++k) best[k] = ~0ull;

  for (int j = u; j < N_PTS; j += 32) {
    float dx = __fsub_rn(px, sx[j]);
    float dy = __fsub_rn(py, sy[j]);
    float dz = __fsub_rn(pz, sz[j]);
    float d2 = __builtin_fmaf(dz, dz,
                 __builtin_fmaf(dx, dx, __fmul_rn(dy, dy)));
    float d = __fsqrt_rn(fmaxf(d2, 0.0f));
    unsigned long long key = (((unsigned long long)__float_as_uint(d)) << 32)
                           | (unsigned)j;
    if (key < best[5]) {
      best[5] = key;
#pragma unroll
      for (int k = 5; k >= 1; --k)
        if (best[k] < best[k - 1]) {
          unsigned long long t = best[k]; best[k] = best[k - 1]; best[k - 1] = t;
        }
    }
  }

  // 6-round extract-min across the 32-lane group (keys unique)
  int h = 0;
  unsigned long long win[6];
#pragma unroll
  for (int round = 0; round < 6; ++round) {
    unsigned long long my = (h < 6) ? best[h] : ~0ull;
    unsigned long long m = my;
#pragma unroll
    for (int msk = 16; msk >= 1; msk >>= 1) {
      unsigned long long o = shflxor64(m, msk);
      if (o < m) m = o;
    }
    win[round] = m;
    if (my == m) ++h;
  }

  if (u == 0) {
#pragma unroll
    for (int m = 1; m <= NK; ++m) {     // drop win[0] == self (d = 0)
      oidx[p * NK + m - 1]  = (int)(win[m] & 0xFFFFFFFFull);
      odist[p * NK + m - 1] = __uint_as_float((unsigned)(win[m] >> 32));
    }
  }
}

// Shared staging + cell loop. PASS 0 = rowmax (atomic-free), PASS 1 = collect.
template <int PASS>
__device__ __forceinline__ void pa_pass(
    const float* __restrict__ L,
    const int* __restrict__ sidx, const float* __restrict__ sdist,
    const int* __restrict__ ridx, const float* __restrict__ rdist,
    int s, int tid, float (&A)[NK][N_PTS],
    unsigned int* rowmax_out,                  // PASS 0
    unsigned int T, unsigned int* counters,    // PASS 1
    uint64_t* cand, unsigned int cap) {
  __shared__ float sdsh[NK];
  __shared__ int   snsh[NK];
  __shared__ unsigned int red[256];
  if (tid < NK) { snsh[tid] = sidx[s * NK + tid]; sdsh[tid] = sdist[s * NK + tid]; }
  __syncthreads();
#pragma unroll
  for (int i = 0; i < NK; ++i) {
    const int row = snsh[i];
    for (int c = tid; c < N_PTS; c += 256) A[i][c] = L[row * N_PTS + c];
  }
  __syncthreads();
  float sd[NK];
#pragma unroll
  for (int i = 0; i < NK; ++i) sd[i] = sdsh[i];

  unsigned int mymax = 0;
  for (int r = tid; r < N_PTS; r += 256) {
    const float Lsr = L[s * N_PTS + r];
    float rd[NK]; int rn[NK];
#pragma unroll
    for (int j = 0; j < NK; ++j) { rd[j] = rdist[r * NK + j]; rn[j] = ridx[r * NK + j]; }
#pragma unroll
    for (int i = 0; i < NK; ++i) {
#pragma unroll
      for (int j = 0; j < NK; ++j) {
        float diff = __fsub_rn(sd[i], rd[j]);
        float dsq  = __fmul_rn(diff, diff);
        // prefilter: dsq >= 0.0101f  =>  q > 1  =>  temp = 0  (skip IEEE div)
        if (dsq < 0.0101f) {
          float q    = __fdiv_rn(dsq, 0.01f);
          float temp = fmaxf(__fsub_rn(1.0f, q), 0.0f);
          if (temp > 0.0f) {
            float v = __fmul_rn(__fmul_rn(Lsr, temp), A[i][rn[j]]);
            unsigned int vb = __float_as_uint(v);
            if (PASS == 0) {
              if (vb > mymax) mymax = vb;      // v >= 0: bits monotone, 0 ignored
            } else {
              if (v > 0.0f && vb >= T) {
                unsigned int pos = atomicAdd(&counters[0], 1u);
                if (pos < cap) {
                  unsigned int idx = ((unsigned int)(s * N_PTS + r)) * 25u
                                   + (unsigned int)(i * NK + j);
                  cand[pos] = (((uint64_t)vb) << 32) | (uint64_t)((uint32_t)(~idx));
                }
              }
            }
          }
        }
      }
    }
  }
  if (PASS == 0) {
    red[tid] = mymax;
    __syncthreads();
    for (int step = 128; step > 0; step >>= 1) {
      if (tid < step && red[tid + step] > red[tid]) red[tid] = red[tid + step];
      __syncthreads();
    }
    if (tid == 0) rowmax_out[s] = red[0];
  }
}

// ---------------- pass 1: per-row max (no atomics) ---------------------------
__global__ __launch_bounds__(256) void rowmax_kernel(
    const float* __restrict__ L,
    const int* __restrict__ sidx, const float* __restrict__ sdist,
    const int* __restrict__ ridx, const float* __restrict__ rdist,
    unsigned int* __restrict__ rowmax) {
  __shared__ float A[NK][N_PTS];
  pa_pass<0>(L, sidx, sdist, ridx, rdist, blockIdx.x, threadIdx.x, A,
             rowmax, 0, nullptr, nullptr, 0);
}

// ---------------- threshold: T = 512th-largest row max; zero counter ---------
// count(v >= T) >= 512 guaranteed: each of the top-512 rows contributes >= 1.
__global__ __launch_bounds__(1024) void thresh_kernel(
    const unsigned int* __restrict__ rowmax, unsigned int* __restrict__ counters) {
  __shared__ unsigned int a[N_PTS];
  const int tid = threadIdx.x;
  for (int t = tid; t < N_PTS; t += 1024) a[t] = rowmax[t];
  __syncthreads();
  // bitonic sort descending, 2048 elems, 2 per thread
  for (int k2 = 2; k2 <= N_PTS; k2 <<= 1) {
    for (int j2 = k2 >> 1; j2 > 0; j2 >>= 1) {
      for (int e = 0; e < N_PTS / 1024; ++e) {
        int i = tid + e * 1024;
        int pj = i ^ j2;
        if (pj > i) {
          bool blk = ((i & k2) == 0);
          unsigned int x = a[i], y = a[pj];
          if (blk ? (x < y) : (x > y)) { a[i] = y; a[pj] = x; }
        }
      }
      __syncthreads();
    }
  }
  if (tid == 0) {
    counters[3] = a[TOPK - 1];
    counters[0] = 0;
  }
}

// ---------------- pass 2: collect (vb, ~idx) with vb >= T --------------------
__global__ __launch_bounds__(256) void collect_kernel(
    const float* __restrict__ L,
    const int* __restrict__ sidx, const float* __restrict__ sdist,
    const int* __restrict__ ridx, const float* __restrict__ rdist,
    unsigned int* __restrict__ counters, uint64_t* __restrict__ cand,
    unsigned int cap) {
  __shared__ float A[NK][N_PTS];
  const unsigned int T = counters[3];
  pa_pass<1>(L, sidx, sdist, ridx, rdist, blockIdx.x, threadIdx.x, A,
             nullptr, T, counters, cand, cap);
}

// ---------------- exact top-512: byte radix-select + bitonic sort ------------
// key=(vb<<32)|~idx descending == value desc, idx asc on ties (r9-verified).
__global__ __launch_bounds__(1024) void select_kernel(
    const uint64_t* __restrict__ cand, const unsigned int* __restrict__ counters,
    const int* __restrict__ sidx, const int* __restrict__ ridx,
    int* __restrict__ out, unsigned int cap) {
  __shared__ unsigned int h[256];
  __shared__ uint64_t topk[TOPK];
  __shared__ unsigned int cnt2;
  __shared__ uint64_t sh_prefix;
  __shared__ unsigned int sh_k;
  const int tid = threadIdx.x;
  unsigned int n = counters[0];
  if (n > cap) n = cap;
  if (tid == 0) { sh_prefix = 0; sh_k = TOPK; cnt2 = 0; }

  for (int byte = 7; byte >= 0; --byte) {
    for (int b = tid; b < 256; b += 1024) h[b] = 0;
    __syncthreads();
    const uint64_t prefix = sh_prefix;
    const uint64_t mask = (byte == 7) ? 0ull : (~0ull << (8 * (byte + 1)));
    for (unsigned int i = tid; i < n; i += 1024) {
      uint64_t key = cand[i];
      if ((key & mask) == prefix)
        atomicAdd(&h[(unsigned int)(key >> (8 * byte)) & 255u], 1u);
    }
    __syncthreads();
    if (tid == 0) {
      unsigned int k = sh_k, cum = 0; int chosen = 0;
      for (int v = 255; v >= 0; --v) {
        if (cum + h[v] >= k) { chosen = v; sh_k = k - cum; break; }
        cum += h[v];
      }
      sh_prefix = prefix | (((uint64_t)chosen) << (8 * byte));
    }
    __syncthreads();
  }
  const uint64_t kstar = sh_prefix;

  for (int t = tid; t < TOPK; t += 1024) topk[t] = 0;
  __syncthreads();
  for (unsigned int i = tid; i < n; i += 1024) {
    uint64_t key = cand[i];
    if (key >= kstar) {
      unsigned int pos = atomicAdd(&cnt2, 1u);
      if (pos < TOPK) topk[pos] = key;
    }
  }
  __syncthreads();

  for (int k2 = 2; k2 <= TOPK; k2 <<= 1) {
    for (int j2 = k2 >> 1; j2 > 0; j2 >>= 1) {
      if (tid < TOPK) {
        int ixj = tid ^ j2;
        if (ixj > tid) {
          bool asc = ((tid & k2) == 0);
          uint64_t a = topk[tid], b = topk[ixj];
          if (asc ? (a < b) : (a > b)) { topk[tid] = b; topk[ixj] = a; }
        }
      }
      __syncthreads();
    }
  }

  if (tid < TOPK) {
    uint64_t key = topk[tid];
    unsigned int idx = ~((unsigned int)key);
    if (idx >= 104857600u) idx = 0;           // safety clamp (degenerate only)
    unsigned int s   = idx / 51200u;          // n_r*K*K = 2048*25
    unsigned int rem = idx % 51200u;
    unsigned int r   = rem / 25u;
    unsigned int sij = rem % 25u;
    out[0 * TOPK + tid] = (int)s;                       // first_node_src
    out[1 * TOPK + tid] = (int)r;                       // first_node_ref
    out[2 * TOPK + tid] = sidx[s * NK + sij / 5u];      // second_node_src
    out[3 * TOPK + tid] = ridx[r * NK + sij % 5u];      // second_node_ref
  }
}

extern "C" void kernel_launch(void* const* d_in, const int* in_sizes, int n_in,
                              void* d_out, int out_size, void* d_ws, size_t ws_size,
                              hipStream_t stream) {
  const float* src = (const float*)d_in[0];
  const float* ref = (const float*)d_in[1];
  const float* L   = (const float*)d_in[2];
  char* ws = (char*)d_ws;
  int*          sidx  = (int*)(ws + OFF_SIDX);
  float*        sdist = (float*)(ws + OFF_SDIST);
  int*          ridx  = (int*)(ws + OFF_RIDX);
  float*        rdist = (float*)(ws + OFF_RDIST);
  unsigned int* rmax  = (unsigned int*)(ws + OFF_RMAX);
  unsigned int* cnts  = (unsigned int*)(ws + OFF_CNT);
  uint64_t*     cand  = (uint64_t*)(ws + OFF_CAND);
  int*          out   = (int*)d_out;

  unsigned int cap = 0;
  if (ws_size > (size_t)OFF_CAND + 8) {
    size_t c = (ws_size - (size_t)OFF_CAND) / 8;
    cap = (c > CAP_MAX) ? CAP_MAX : (unsigned int)c;
  }

  knn_kernel<<<512, 256, 0, stream>>>(src, ref, sidx, sdist, ridx, rdist);
  rowmax_kernel<<<N_PTS, 256, 0, stream>>>(L, sidx, sdist, ridx, rdist, rmax);
  thresh_kernel<<<1, 1024, 0, stream>>>(rmax, cnts);
  collect_kernel<<<N_PTS, 256, 0, stream>>>(L, sidx, sdist, ridx, rdist, cnts, cand, cap);
  select_kernel<<<1, 1024, 0, stream>>>(cand, cnts, sidx, ridx, out, cap);
}